// Round 1
// baseline (17709.369 us; speedup 1.0000x reference)
//
#include <hip/hip_runtime.h>

typedef _Float16 half_t;
typedef _Float16 half8 __attribute__((ext_vector_type(8)));
typedef _Float16 half4 __attribute__((ext_vector_type(4)));
typedef float float4v __attribute__((ext_vector_type(4)));

#define BB    256   // batch
#define SS    512   // seq len
#define IND   64    // input dim
#define HH    1024  // hidden
#define G4    4096  // 4*H
#define KTOT  1088  // H + IN (packed K)
#define HEADD 128
#define OUTD  64

// ---------- prologue packs ----------

// Pack [W_hh | W_ih] -> fp16 [4096][1088], row-major K-contiguous.
__global__ __launch_bounds__(256) void pack_w_kernel(
    const float* __restrict__ W_hh, const float* __restrict__ W_ih,
    half_t* __restrict__ Wp) {
  int n = blockIdx.x;  // 0..4095
  for (int k = threadIdx.x; k < KTOT; k += 256) {
    float v = (k < HH) ? W_hh[n * HH + k] : W_ih[n * IND + (k - HH)];
    Wp[(size_t)n * KTOT + k] = (half_t)v;
  }
}

// Generic fp32 -> fp16 row pack (one block per row).
__global__ __launch_bounds__(256) void pack_mat_kernel(
    const float* __restrict__ src, half_t* __restrict__ dst, int ncols) {
  int n = blockIdx.x;
  for (int k = threadIdx.x; k < ncols; k += 256)
    dst[(size_t)n * ncols + k] = (half_t)src[(size_t)n * ncols + k];
}

// x[B][S][IN] fp32 -> xT[S][B][IN] fp16 (time-major so each step slice is contiguous)
__global__ __launch_bounds__(256) void pack_x_kernel(
    const float* __restrict__ x, half_t* __restrict__ xT) {
  int gp = blockIdx.x * 4 + (threadIdx.x >> 6);  // (b,s) pair index
  int i  = threadIdx.x & 63;
  int b = gp >> 9;       // /512
  int s = gp & 511;
  xT[((size_t)s * BB + b) * IND + i] = (half_t)x[((size_t)b * SS + s) * IND + i];
}

// ---------- per-step fused kernel ----------
// blocks 0..255  : gates GEMM (64 rows x 16 h-cols x 4 gates) + cell update -> hnext, c
// blocks 256..271: dense head for h_{t-1} (16 rows each) -> out[:, t-1, :]
__global__ __launch_bounds__(256) void step_kernel(
    const half_t* __restrict__ Wp, const half_t* __restrict__ xT,
    const float* __restrict__ b_ih, const float* __restrict__ b_hh,
    const half_t* __restrict__ Wd, const float* __restrict__ bd,
    const half_t* __restrict__ Wd2, const float* __restrict__ bd2,
    half_t* __restrict__ hbufs, float* __restrict__ c,
    float* __restrict__ out, int t) {
  const int bid  = blockIdx.x;
  const int tid  = threadIdx.x;
  const int wave = tid >> 6;
  const int lane = tid & 63;
  const int rn   = lane & 15;   // row (A) / col (B) within fragment
  const int quad = lane >> 4;   // k-quad
  const half_t* __restrict__ hprev = hbufs + (size_t)(t & 1) * BB * HH;
  half_t* __restrict__ hnext       = hbufs + (size_t)((t + 1) & 1) * BB * HH;

  if (bid < 256) {
    if (t >= SS) return;
    __shared__ float pre[4][64][16];  // [gate][m_local][n_local]
    const int mtile = bid >> 6;      // 0..3
    const int jtile = bid & 63;      // 0..63
    const int m0 = mtile * 64;
    const int j0 = jtile * 16;

    // each wave owns one gate: W rows n = wave*H + j0 + rn
    const half_t* __restrict__ wrow =
        Wp + (size_t)(wave * HH + j0 + rn) * KTOT + quad * 8;

    float4v acc0 = {0.f, 0.f, 0.f, 0.f};
    float4v acc1 = {0.f, 0.f, 0.f, 0.f};
    float4v acc2 = {0.f, 0.f, 0.f, 0.f};
    float4v acc3 = {0.f, 0.f, 0.f, 0.f};

    const half_t* __restrict__ a0 = hprev + (size_t)(m0 + rn) * HH + quad * 8;
    #pragma unroll 8
    for (int k0 = 0; k0 < HH; k0 += 32) {
      half8 bf = *(const half8*)(wrow + k0);
      acc0 = __builtin_amdgcn_mfma_f32_16x16x32_f16(*(const half8*)(a0 + k0), bf, acc0, 0, 0, 0);
      acc1 = __builtin_amdgcn_mfma_f32_16x16x32_f16(*(const half8*)(a0 + 16 * HH + k0), bf, acc1, 0, 0, 0);
      acc2 = __builtin_amdgcn_mfma_f32_16x16x32_f16(*(const half8*)(a0 + 32 * HH + k0), bf, acc2, 0, 0, 0);
      acc3 = __builtin_amdgcn_mfma_f32_16x16x32_f16(*(const half8*)(a0 + 48 * HH + k0), bf, acc3, 0, 0, 0);
    }
    // x_t contribution (K = 1024..1087)
    const half_t* __restrict__ xb =
        xT + (size_t)t * BB * IND + (size_t)(m0 + rn) * IND + quad * 8;
    #pragma unroll
    for (int k0 = 0; k0 < IND; k0 += 32) {
      half8 bf = *(const half8*)(wrow + HH + k0);
      acc0 = __builtin_amdgcn_mfma_f32_16x16x32_f16(*(const half8*)(xb + k0), bf, acc0, 0, 0, 0);
      acc1 = __builtin_amdgcn_mfma_f32_16x16x32_f16(*(const half8*)(xb + 16 * IND + k0), bf, acc1, 0, 0, 0);
      acc2 = __builtin_amdgcn_mfma_f32_16x16x32_f16(*(const half8*)(xb + 32 * IND + k0), bf, acc2, 0, 0, 0);
      acc3 = __builtin_amdgcn_mfma_f32_16x16x32_f16(*(const half8*)(xb + 48 * IND + k0), bf, acc3, 0, 0, 0);
    }

    #pragma unroll
    for (int r = 0; r < 4; ++r) {
      pre[wave][ 0 + quad * 4 + r][rn] = acc0[r];
      pre[wave][16 + quad * 4 + r][rn] = acc1[r];
      pre[wave][32 + quad * 4 + r][rn] = acc2[r];
      pre[wave][48 + quad * 4 + r][rn] = acc3[r];
    }
    __syncthreads();

    // cell update: thread -> (m = tid>>2, 4 consecutive cols)
    const int m  = tid >> 2;        // 0..63
    const int n4 = (tid & 3) * 4;   // 0,4,8,12
    const int grow = m0 + m;
    const int gcol = j0 + n4;
    float4v cold = *(const float4v*)(c + (size_t)grow * HH + gcol);
    float4v cnew;
    half4 hnew;
    #pragma unroll
    for (int jj = 0; jj < 4; ++jj) {
      const int col = n4 + jj;
      const int gc  = j0 + col;
      float ig = pre[0][m][col] + b_ih[gc]          + b_hh[gc];
      float fg = pre[1][m][col] + b_ih[HH + gc]     + b_hh[HH + gc];
      float gg = pre[2][m][col] + b_ih[2 * HH + gc] + b_hh[2 * HH + gc];
      float og = pre[3][m][col] + b_ih[3 * HH + gc] + b_hh[3 * HH + gc];
      float is = 1.f / (1.f + __expf(-ig));
      float fs = 1.f / (1.f + __expf(-fg));
      float os = 1.f / (1.f + __expf(-og));
      float gt = tanhf(gg);
      float cn = fs * cold[jj] + is * gt;
      cnew[jj] = cn;
      hnew[jj] = (half_t)(os * tanhf(cn));
    }
    *(float4v*)(c + (size_t)grow * HH + gcol) = cnew;
    *(half4*)(hnext + (size_t)grow * HH + gcol) = hnew;
  } else {
    // ---- dense head for previous step ----
    if (t == 0) return;
    __shared__ half_t dls[16][HEADD];
    const int r0 = (bid - 256) * 16;

    // dense1: d[16][128] = relu(h[16][1024] @ Wd^T + bd); wave owns cols wave*32..+31
    float4v d0 = {0.f, 0.f, 0.f, 0.f};
    float4v d1 = {0.f, 0.f, 0.f, 0.f};
    const half_t* __restrict__ arow = hprev + (size_t)(r0 + rn) * HH + quad * 8;
    const half_t* __restrict__ bw0  = Wd + (size_t)(wave * 32 + rn) * HH + quad * 8;
    const half_t* __restrict__ bw1  = bw0 + (size_t)16 * HH;
    #pragma unroll 8
    for (int k0 = 0; k0 < HH; k0 += 32) {
      half8 af = *(const half8*)(arow + k0);
      d0 = __builtin_amdgcn_mfma_f32_16x16x32_f16(af, *(const half8*)(bw0 + k0), d0, 0, 0, 0);
      d1 = __builtin_amdgcn_mfma_f32_16x16x32_f16(af, *(const half8*)(bw1 + k0), d1, 0, 0, 0);
    }
    #pragma unroll
    for (int r = 0; r < 4; ++r) {
      const int rloc = quad * 4 + r;
      const int c0 = wave * 32 + rn;
      const int c1 = c0 + 16;
      dls[rloc][c0] = (half_t)fmaxf(d0[r] + bd[c0], 0.f);
      dls[rloc][c1] = (half_t)fmaxf(d1[r] + bd[c1], 0.f);
    }
    __syncthreads();

    // dense2: pred[16][64] = d @ Wd2^T + bd2; wave owns out cols wave*16..+15
    float4v p = {0.f, 0.f, 0.f, 0.f};
    const half_t* __restrict__ bw2 = Wd2 + (size_t)(wave * 16 + rn) * HEADD + quad * 8;
    #pragma unroll
    for (int k0 = 0; k0 < HEADD; k0 += 32) {
      half8 af = *(const half8*)(&dls[rn][k0 + quad * 8]);
      p = __builtin_amdgcn_mfma_f32_16x16x32_f16(af, *(const half8*)(bw2 + k0), p, 0, 0, 0);
    }
    #pragma unroll
    for (int r = 0; r < 4; ++r) {
      const int prow = r0 + quad * 4 + r;
      const int pcol = wave * 16 + rn;
      out[(size_t)prow * (SS * OUTD) + (size_t)(t - 1) * OUTD + pcol] = p[r] + bd2[pcol];
    }
  }
}

extern "C" void kernel_launch(void* const* d_in, const int* in_sizes, int n_in,
                              void* d_out, int out_size, void* d_ws, size_t ws_size,
                              hipStream_t stream) {
  const float* x        = (const float*)d_in[0];
  const float* W_ih     = (const float*)d_in[1];
  const float* b_ih     = (const float*)d_in[2];
  const float* W_hh     = (const float*)d_in[3];
  const float* b_hh     = (const float*)d_in[4];
  const float* W_dense  = (const float*)d_in[5];
  const float* b_dense  = (const float*)d_in[6];
  const float* W_dense2 = (const float*)d_in[7];
  const float* b_dense2 = (const float*)d_in[8];
  float* out = (float*)d_out;

  char* p = (char*)d_ws;
  half_t* Wp   = (half_t*)p; p += (size_t)G4 * KTOT * 2;     // 8.9 MB
  half_t* Wd   = (half_t*)p; p += (size_t)HEADD * HH * 2;    // 256 KB
  half_t* Wd2  = (half_t*)p; p += (size_t)OUTD * HEADD * 2;  // 16 KB
  half_t* xT   = (half_t*)p; p += (size_t)SS * BB * IND * 2; // 16.8 MB
  half_t* hbuf = (half_t*)p; p += (size_t)2 * BB * HH * 2;   // 1 MB
  float*  c    = (float*)p;  p += (size_t)BB * HH * 4;       // 1 MB

  hipMemsetAsync(hbuf, 0, (size_t)2 * BB * HH * 2, stream);
  hipMemsetAsync(c, 0, (size_t)BB * HH * 4, stream);
  pack_w_kernel<<<G4, 256, 0, stream>>>(W_hh, W_ih, Wp);
  pack_mat_kernel<<<HEADD, 256, 0, stream>>>(W_dense, Wd, HH);
  pack_mat_kernel<<<OUTD, 256, 0, stream>>>(W_dense2, Wd2, HEADD);
  pack_x_kernel<<<BB * SS / 4, 256, 0, stream>>>(x, xT);

  // t = 0..SS inclusive: step t computes h_t / c_t (t<SS) and pred_{t-1} (t>0).
  for (int t = 0; t <= SS; ++t) {
    step_kernel<<<272, 256, 0, stream>>>(Wp, xT, b_ih, b_hh, Wd, b_dense,
                                         Wd2, b_dense2, hbuf, c, out, t);
  }
}